// Round 10
// baseline (434.949 us; speedup 1.0000x reference)
//
#include <hip/hip_runtime.h>
#include <hip/hip_bf16.h>
#include <stdint.h>

#define BB 2
#define SS 2048
#define DDIM 1024
#define HH 16
#define HDIM 64
#define NC 4          // KV chunks (split-K)
#define CK 512        // keys per chunk
#define NROW 65536    // B*H*S q-rows

typedef __hip_bfloat16 bf16;
typedef __bf16 bf16x8 __attribute__((ext_vector_type(8)));
typedef float f32x4 __attribute__((ext_vector_type(4)));
typedef int i32x4 __attribute__((ext_vector_type(4)));
typedef short short8 __attribute__((ext_vector_type(8)));
typedef short s16x4 __attribute__((ext_vector_type(4)));

static __device__ __forceinline__ f32x4 mfma16(bf16x8 a, bf16x8 b, f32x4 c) {
  return __builtin_amdgcn_mfma_f32_16x16x32_bf16(a, b, c, 0, 0, 0);
}

static __device__ __forceinline__ void gload_lds16(const void* g, void* l) {
  __builtin_amdgcn_global_load_lds(
      (const __attribute__((address_space(1))) void*)g,
      (__attribute__((address_space(3))) void*)l, 16, 0, 0);
}

// ---------------- f32 -> bf16 flat convert (8 elems/thread) ----------------
__global__ __launch_bounds__(256) void cvt_k(const float* __restrict__ src,
                                             bf16* __restrict__ dst) {
  const int base = (blockIdx.x * 256 + threadIdx.x) * 8;
  float4 a = *reinterpret_cast<const float4*>(src + base);
  float4 b = *reinterpret_cast<const float4*>(src + base + 4);
  union {
    bf16 h[8];
    short8 v;
  } u;
  u.h[0] = __float2bfloat16(a.x);
  u.h[1] = __float2bfloat16(a.y);
  u.h[2] = __float2bfloat16(a.z);
  u.h[3] = __float2bfloat16(a.w);
  u.h[4] = __float2bfloat16(b.x);
  u.h[5] = __float2bfloat16(b.y);
  u.h[6] = __float2bfloat16(b.z);
  u.h[7] = __float2bfloat16(b.w);
  *reinterpret_cast<short8*>(dst + base) = u.v;
}

// ------------- transpose+convert: dst[n][k] = (bf16)src[k][n], 1024x1024 ----
__global__ __launch_bounds__(256) void transpose_cvt_k(
    const float* __restrict__ src, bf16* __restrict__ dst) {
  __shared__ float tile[64][65];
  const int t = threadIdx.x;
  const int r = t >> 2, c0 = (t & 3) * 16;
  const int bx = blockIdx.x * 64, by = blockIdx.y * 64;
  const float* sp = src + (size_t)(by + r) * DDIM + bx + c0;
#pragma unroll
  for (int j = 0; j < 16; ++j) tile[r][c0 + j] = sp[j];
  __syncthreads();
  bf16* dp = dst + (size_t)(bx + r) * DDIM + by + c0;
#pragma unroll
  for (int j = 0; j < 16; ++j) dp[j] = __float2bfloat16(tile[c0 + j][r]);
}

// ---------------- GEMM: C[m][n] = A[m][:] . Bt[n][:]  (row-major, K=1024)
// MODE 0: N=3072, scatter bf16 to Q / K / Vt with per-section f32 bias
// MODE 1: N=1024, write f32 Of[m*1024+n] + bias b0
template <int MODE>
__global__ __launch_bounds__(256, 2) void gemm_bt(
    const bf16* __restrict__ A, const bf16* __restrict__ Bt,
    const float* __restrict__ b0, const float* __restrict__ b1,
    const float* __restrict__ b2, bf16* __restrict__ O0,
    bf16* __restrict__ O1, bf16* __restrict__ O2, float* __restrict__ Of) {
  constexpr int Kd = DDIM;
  __shared__ bf16x8 lA[128 * 8];
  __shared__ bf16x8 lB[128 * 8];
  const int tid = threadIdx.x;
  const int wave = tid >> 6, lane = tid & 63;
  const int l15 = lane & 15, l4 = lane >> 4;
  const int wm = wave >> 1, wn = wave & 1;
  const int m0 = blockIdx.x * 128, n0 = blockIdx.y * 128;
  const f32x4 z = {0.f, 0.f, 0.f, 0.f};
  f32x4 acc[4][4];
#pragma unroll
  for (int i = 0; i < 4; ++i)
#pragma unroll
    for (int j = 0; j < 4; ++j) acc[i][j] = z;

  for (int k0 = 0; k0 < Kd; k0 += 64) {
#pragma unroll
    for (int j = 0; j < 4; ++j) {
      const int slot = j * 256 + tid;
      const int r = slot >> 3, cs = slot & 7;
      const int c = cs ^ (r & 7);  // pre-swizzled global source, linear LDS dest
      gload_lds16(A + (size_t)(m0 + r) * Kd + k0 + c * 8,
                  &lA[j * 256 + wave * 64]);
      gload_lds16(Bt + (size_t)(n0 + r) * Kd + k0 + c * 8,
                  &lB[j * 256 + wave * 64]);
    }
    __syncthreads();
    bf16x8 af[2][4], bfr[2][4];
#pragma unroll
    for (int ks = 0; ks < 2; ++ks) {
#pragma unroll
      for (int i = 0; i < 4; ++i) {
        const int ra = wm * 64 + i * 16 + l15;
        af[ks][i] = lA[ra * 8 + ((ks * 4 + l4) ^ (ra & 7))];
        const int rb = wn * 64 + i * 16 + l15;
        bfr[ks][i] = lB[rb * 8 + ((ks * 4 + l4) ^ (rb & 7))];
      }
    }
#pragma unroll
    for (int ks = 0; ks < 2; ++ks)
#pragma unroll
      for (int i = 0; i < 4; ++i)
#pragma unroll
        for (int j = 0; j < 4; ++j)
          acc[i][j] = mfma16(af[ks][i], bfr[ks][j], acc[i][j]);
    __syncthreads();
  }

  // C row m = m0 + wm*64 + i*16 + l4*4 + r ; col n = n0 + wn*64 + j*16 + l15
#pragma unroll
  for (int i = 0; i < 4; ++i) {
    const int m = m0 + wm * 64 + i * 16 + l4 * 4;
#pragma unroll
    for (int j = 0; j < 4; ++j) {
      const int n = n0 + wn * 64 + j * 16 + l15;
      if (MODE == 1) {
        const float bb = b0[n];
#pragma unroll
        for (int r = 0; r < 4; ++r)
          Of[(size_t)(m + r) * DDIM + n] = acc[i][j][r] + bb;
      } else {
        const int sel = n >> 10, nn = n & 1023;
        const int h = nn >> 6, d = nn & 63;
        const float* bp = sel == 0 ? b0 : (sel == 1 ? b1 : b2);
        const float bb = bp[nn];
        const int b = m >> 11, s = m & 2047;
        if (sel == 2) {
          union {
            bf16 h4[4];
            s16x4 v;
          } u;
#pragma unroll
          for (int r = 0; r < 4; ++r)
            u.h4[r] = __float2bfloat16(acc[i][j][r] + bb);
          *reinterpret_cast<s16x4*>(
              &O2[((size_t)(b * HH + h) * HDIM + d) * SS + s]) = u.v;
        } else {
#pragma unroll
          for (int r = 0; r < 4; ++r) {
            const float val = acc[i][j][r] + bb;
            (sel ? O1 : O0)[((size_t)(b * HH + h) * SS + (s + r)) * HDIM + d] =
                __float2bfloat16(val);
          }
        }
      }
    }
  }
}

// -------- fused flash attention, split-K over 4 KV chunks (swapped QK^T) ----
// grid.x = B*H*32*NC; block = 256 (4 waves), wave owns 16 q-rows, chunk = 512
// keys. Writes UNNORMALIZED partials (o, m, l) per chunk; merge_k combines.
__global__ __launch_bounds__(256, 3) void attn_k(
    const bf16* __restrict__ Qb, const bf16* __restrict__ Kb,
    const bf16* __restrict__ Vt, const float* __restrict__ bias,
    const int* __restrict__ kpm, float* __restrict__ Om,
    float* __restrict__ Ml) {
  __shared__ unsigned int pl[4 * 512];  // 4 waves x 2KB P scratch
  const int wave = threadIdx.x >> 6, lane = threadIdx.x & 63;
  const int l15 = lane & 15, l4 = lane >> 4;
  const int bid = blockIdx.x;
  const int c = bid & 3, qblk = (bid >> 2) & 31, bh = bid >> 7;
  const int b = bh >> 4, h = bh & 15;
  const int q0w = qblk * 64 + wave * 16;
  const int k0c = c * CK;

  const bf16* Qp = Qb + ((size_t)bh * SS + q0w) * HDIM;
  const bf16* Kp = Kb + ((size_t)bh * SS + k0c) * HDIM;
  const bf16* Vp = Vt + (size_t)bh * HDIM * SS + k0c;
  const float* Bp =
      bias + (size_t)h * SS * SS + (size_t)(q0w + l15) * SS + k0c;
  const int* mp = kpm + b * SS + k0c;
  unsigned int* plw = pl + wave * 512;

  bf16x8 qf[2];
#pragma unroll
  for (int ks = 0; ks < 2; ++ks)
    qf[ks] = *reinterpret_cast<const bf16x8*>(Qp + (size_t)l15 * HDIM +
                                              ks * 32 + l4 * 8);
  const f32x4 z = {0.f, 0.f, 0.f, 0.f};
  f32x4 o[4];
#pragma unroll
  for (int dd = 0; dd < 4; ++dd) o[dd] = z;
  float mrow = -1e30f, lrow = 0.f;

  // load bias[q=l15][k..k+3] + mask, fold: addend = masked ? -1e30 : bias
  auto ldadd = [&](int kl, f32x4 (&dst)[4]) {
#pragma unroll
    for (int jj = 0; jj < 4; ++jj) {
      const int kc = kl + jj * 16 + l4 * 4;
      f32x4 bv = *reinterpret_cast<const f32x4*>(Bp + kc);
      i32x4 mv = *reinterpret_cast<const i32x4*>(mp + kc);
      f32x4 a;
#pragma unroll
      for (int r = 0; r < 4; ++r) a[r] = mv[r] ? -1e30f : bv[r];
      dst[jj] = a;
    }
  };

  f32x4 addA[4], addB[4];
  ldadd(0, addA);

  auto step = [&](int t, const f32x4 (&cur)[4], f32x4 (&nxt)[4]) {
    const int kl = t * 64;
    const int kln = (kl + 64) & (CK - 1);
    // 1) prefetch next addend
    ldadd(kln, nxt);
    // 2) K fragments
    bf16x8 kf[4][2];
#pragma unroll
    for (int jj = 0; jj < 4; ++jj)
#pragma unroll
      for (int ks = 0; ks < 2; ++ks)
        kf[jj][ks] = *reinterpret_cast<const bf16x8*>(
            Kp + (size_t)(kl + jj * 16 + l15) * HDIM + ks * 32 + l4 * 8);
    // 3) swapped QK^T: sc[jj][r] = S[k=kl+jj*16+l4*4+r][q=l15]
    f32x4 sc[4];
#pragma unroll
    for (int jj = 0; jj < 4; ++jj) {
      f32x4 s = z;
#pragma unroll
      for (int ks = 0; ks < 2; ++ks) s = mfma16(kf[jj][ks], qf[ks], s);
      sc[jj] = s;
    }
    // 4) V fragments; latency hides under softmax
    bf16x8 vf[4][2];
#pragma unroll
    for (int dd = 0; dd < 4; ++dd)
#pragma unroll
      for (int ks = 0; ks < 2; ++ks)
        vf[dd][ks] = *reinterpret_cast<const bf16x8*>(
            Vp + (size_t)(dd * 16 + l15) * SS + kl + ks * 32 + l4 * 8);
    // 5) softmax (lane-local row q=l15)
    float v[4][4];
    float bm = -1e30f;
#pragma unroll
    for (int jj = 0; jj < 4; ++jj)
#pragma unroll
      for (int r = 0; r < 4; ++r) {
        v[jj][r] = fmaf(sc[jj][r], 0.125f, cur[jj][r]);
        bm = fmaxf(bm, v[jj][r]);
      }
    bm = fmaxf(bm, __shfl_xor(bm, 16));
    bm = fmaxf(bm, __shfl_xor(bm, 32));
    const float mn = fmaxf(mrow, bm);
    const float alpha = __expf(mrow - mn);
    mrow = mn;
    float ps = 0.f;
    float p[4][4];
#pragma unroll
    for (int jj = 0; jj < 4; ++jj)
#pragma unroll
      for (int r = 0; r < 4; ++r) {
        p[jj][r] = __expf(v[jj][r] - mn);
        ps += p[jj][r];
      }
    ps += __shfl_xor(ps, 16);
    ps += __shfl_xor(ps, 32);
    lrow = lrow * alpha + ps;
    // 6) pack P to per-wave LDS (XOR-swizzled)
#pragma unroll
    for (int jj = 0; jj < 4; ++jj)
#pragma unroll
      for (int r0 = 0; r0 < 4; r0 += 2) {
        union {
          bf16 h2[2];
          unsigned int w;
        } u;
        u.h2[0] = __float2bfloat16(p[jj][r0]);
        u.h2[1] = __float2bfloat16(p[jj][r0 + 1]);
        const int byte =
            (l15 * 128 + jj * 32 + l4 * 8 + r0 * 2) ^ ((l15 & 7) << 4);
        plw[byte >> 2] = u.w;
      }
    // 7) read PV A-fragments
    bf16x8 pf[2];
#pragma unroll
    for (int ks = 0; ks < 2; ++ks) {
      const int byte = (l15 * 128 + ks * 64 + l4 * 16) ^ ((l15 & 7) << 4);
      pf[ks] = *reinterpret_cast<const bf16x8*>(
          reinterpret_cast<const char*>(plw) + byte);
    }
    // 8) redistribute alpha, rescale, PV
    float ar[4];
#pragma unroll
    for (int r = 0; r < 4; ++r) ar[r] = __shfl(alpha, l4 * 4 + r);
#pragma unroll
    for (int dd = 0; dd < 4; ++dd) {
#pragma unroll
      for (int r = 0; r < 4; ++r) o[dd][r] *= ar[r];
#pragma unroll
      for (int ks = 0; ks < 2; ++ks) o[dd] = mfma16(pf[ks], vf[dd][ks], o[dd]);
    }
  };

  for (int t2 = 0; t2 < CK / 128; ++t2) {
    step(t2 * 2, addA, addB);
    step(t2 * 2 + 1, addB, addA);
  }

  // epilogue: unnormalized partials
  const size_t Rbase = (size_t)c * NROW + (size_t)bh * SS;
#pragma unroll
  for (int dd = 0; dd < 4; ++dd)
#pragma unroll
    for (int r = 0; r < 4; ++r) {
      const int s = q0w + l4 * 4 + r;
      Om[(Rbase + s) * 64 + dd * 16 + l15] = o[dd][r];
    }
  if (l4 == 0) {
    const size_t R = Rbase + q0w + l15;
    Ml[R * 2] = mrow;
    Ml[R * 2 + 1] = lrow;
  }
}

// ---------------- merge split-K partials -> ctx (bf16) ----------------
// grid = NROW/16 blocks x 256 threads; 16 lanes per q-row, 4 d-elems/lane
__global__ __launch_bounds__(256) void merge_k(const float* __restrict__ Om,
                                               const float* __restrict__ Ml,
                                               bf16* __restrict__ ctx) {
  const int t = threadIdx.x;
  const int row = blockIdx.x * 16 + (t >> 4);
  const int l = t & 15;
  const int bh = row >> 11, s = row & 2047;
  const int b = bh >> 4, h = bh & 15;

  const float m0 = Ml[((size_t)0 * NROW + row) * 2];
  const float l0 = Ml[((size_t)0 * NROW + row) * 2 + 1];
  const float m1 = Ml[((size_t)1 * NROW + row) * 2];
  const float l1 = Ml[((size_t)1 * NROW + row) * 2 + 1];
  const float m2 = Ml[((size_t)2 * NROW + row) * 2];
  const float l2 = Ml[((size_t)2 * NROW + row) * 2 + 1];
  const float m3 = Ml[((size_t)3 * NROW + row) * 2];
  const float l3 = Ml[((size_t)3 * NROW + row) * 2 + 1];
  const float M = fmaxf(fmaxf(m0, m1), fmaxf(m2, m3));
  const float w0 = __expf(m0 - M), w1 = __expf(m1 - M);
  const float w2 = __expf(m2 - M), w3 = __expf(m3 - M);
  const float L = w0 * l0 + w1 * l1 + w2 * l2 + w3 * l3;

  const f32x4 o0 =
      *reinterpret_cast<const f32x4*>(&Om[((size_t)0 * NROW + row) * 64 + l * 4]);
  const f32x4 o1 =
      *reinterpret_cast<const f32x4*>(&Om[((size_t)1 * NROW + row) * 64 + l * 4]);
  const f32x4 o2 =
      *reinterpret_cast<const f32x4*>(&Om[((size_t)2 * NROW + row) * 64 + l * 4]);
  const f32x4 o3 =
      *reinterpret_cast<const f32x4*>(&Om[((size_t)3 * NROW + row) * 64 + l * 4]);
  const float rL = 1.0f / L;
  union {
    bf16 h4[4];
    s16x4 v;
  } u;
#pragma unroll
  for (int r = 0; r < 4; ++r) {
    const float val = (w0 * o0[r] + w1 * o1[r] + w2 * o2[r] + w3 * o3[r]) * rL;
    u.h4[r] = __float2bfloat16(val);
  }
  *reinterpret_cast<s16x4*>(
      &ctx[((size_t)b * SS + s) * DDIM + h * HDIM + l * 4]) = u.v;
}

extern "C" void kernel_launch(void* const* d_in, const int* in_sizes, int n_in,
                              void* d_out, int out_size, void* d_ws,
                              size_t ws_size, hipStream_t stream) {
  const float* x = (const float*)d_in[0];
  const float* abias = (const float*)d_in[1];
  const int* kpm = (const int*)d_in[2];
  const float* Wq = (const float*)d_in[3];
  const float* bq = (const float*)d_in[4];
  const float* Wk = (const float*)d_in[5];
  const float* bk = (const float*)d_in[6];
  const float* Wv = (const float*)d_in[7];
  const float* bv = (const float*)d_in[8];
  const float* Wo = (const float*)d_in[9];
  const float* bo = (const float*)d_in[10];
  float* out = (float*)d_out;

  char* ws = (char*)d_ws;
  bf16* xb = (bf16*)ws;                        // (B,S,D) bf16      8 MB
  bf16* Wt = (bf16*)(ws + 8388608);            // 3072x1024 bf16    6 MB
  bf16* Wot = (bf16*)(ws + 14680064);          // 1024x1024 bf16    2 MB
  bf16* Qb = (bf16*)(ws + 16777216);           // (B,H,S,HD)        8 MB
  bf16* Kb = (bf16*)(ws + 25165824);           // (B,H,S,HD)        8 MB
  bf16* Vtb = (bf16*)(ws + 33554432);          // (B,H,HD,S)        8 MB
  bf16* ctx = (bf16*)(ws + 41943040);          // (B,S,D) bf16      8 MB
  float* Om = (float*)(ws + 50331648);         // 4*65536*64 f32   64 MB
  float* Ml = (float*)(ws + 117440512);        // 4*65536*2 f32     2 MB

  dim3 t256(256);
  cvt_k<<<dim3(2048), t256, 0, stream>>>(x, xb);
  transpose_cvt_k<<<dim3(16, 16), t256, 0, stream>>>(Wq, Wt);
  transpose_cvt_k<<<dim3(16, 16), t256, 0, stream>>>(Wk, Wt + 1024 * 1024);
  transpose_cvt_k<<<dim3(16, 16), t256, 0, stream>>>(Wv, Wt + 2 * 1024 * 1024);
  transpose_cvt_k<<<dim3(16, 16), t256, 0, stream>>>(Wo, Wot);

  gemm_bt<0><<<dim3(32, 24), t256, 0, stream>>>(xb, Wt, bq, bk, bv, Qb, Kb,
                                                Vtb, nullptr);
  attn_k<<<dim3(4096), t256, 0, stream>>>(Qb, Kb, Vtb, abias, kpm, Om, Ml);
  merge_k<<<dim3(4096), t256, 0, stream>>>(Om, Ml, ctx);
  gemm_bt<1><<<dim3(32, 8), t256, 0, stream>>>(ctx, Wot, bo, nullptr, nullptr,
                                               nullptr, nullptr, nullptr, out);
}

// Round 12
// 212.615 us; speedup vs baseline: 2.0457x; 2.0457x over previous
//
#include <hip/hip_runtime.h>
#include <hip/hip_bf16.h>
#include <stdint.h>

#define BB 2
#define SS 2048
#define DDIM 1024
#define HH 16
#define HDIM 64

typedef __hip_bfloat16 bf16;
typedef __bf16 bf16x8 __attribute__((ext_vector_type(8)));
typedef float f32x4 __attribute__((ext_vector_type(4)));
typedef short short8 __attribute__((ext_vector_type(8)));
typedef short s16x4 __attribute__((ext_vector_type(4)));

static __device__ __forceinline__ f32x4 mfma16(bf16x8 a, bf16x8 b, f32x4 c) {
  return __builtin_amdgcn_mfma_f32_16x16x32_bf16(a, b, c, 0, 0, 0);
}

static __device__ __forceinline__ void gload_lds16(const void* g, void* l) {
  __builtin_amdgcn_global_load_lds(
      (const __attribute__((address_space(1))) void*)g,
      (__attribute__((address_space(3))) void*)l, 16, 0, 0);
}

// ---------------- f32 -> bf16 flat convert (8 elems/thread) ----------------
__global__ __launch_bounds__(256) void cvt_k(const float* __restrict__ src,
                                             bf16* __restrict__ dst) {
  const int base = (blockIdx.x * 256 + threadIdx.x) * 8;
  float4 a = *reinterpret_cast<const float4*>(src + base);
  float4 b = *reinterpret_cast<const float4*>(src + base + 4);
  union {
    bf16 h[8];
    short8 v;
  } u;
  u.h[0] = __float2bfloat16(a.x);
  u.h[1] = __float2bfloat16(a.y);
  u.h[2] = __float2bfloat16(a.z);
  u.h[3] = __float2bfloat16(a.w);
  u.h[4] = __float2bfloat16(b.x);
  u.h[5] = __float2bfloat16(b.y);
  u.h[6] = __float2bfloat16(b.z);
  u.h[7] = __float2bfloat16(b.w);
  *reinterpret_cast<short8*>(dst + base) = u.v;
}

// ------------- transpose+convert: dst[n][k] = (bf16)src[k][n], 1024x1024 ----
__global__ __launch_bounds__(256) void transpose_cvt_k(
    const float* __restrict__ src, bf16* __restrict__ dst) {
  __shared__ float tile[64][65];
  const int t = threadIdx.x;
  const int r = t >> 2, c0 = (t & 3) * 16;
  const int bx = blockIdx.x * 64, by = blockIdx.y * 64;
  const float* sp = src + (size_t)(by + r) * DDIM + bx + c0;
#pragma unroll
  for (int j = 0; j < 16; ++j) tile[r][c0 + j] = sp[j];
  __syncthreads();
  bf16* dp = dst + (size_t)(bx + r) * DDIM + by + c0;
#pragma unroll
  for (int j = 0; j < 16; ++j) dp[j] = __float2bfloat16(tile[c0 + j][r]);
}

// ---------------- pack key-padding mask into 64-bit words ----------------
__global__ __launch_bounds__(64) void mask_pack_k(
    const int* __restrict__ kpm, unsigned long long* __restrict__ mb) {
  const int i = threadIdx.x;  // 0..63 : b = i>>5, 64-key chunk = i&31
  const int b = i >> 5, c = i & 31;
  unsigned long long bits = 0ull;
  for (int j = 0; j < 64; ++j)
    bits |= (unsigned long long)(kpm[b * SS + c * 64 + j] != 0) << j;
  mb[i] = bits;
}

// ---------------- GEMM: C[m][n] = A[m][:] . Bt[n][:]  (row-major, K=1024)
// MODE 0: N=3072, scatter bf16 to Q / K / Vt with per-section f32 bias
// MODE 1: N=1024, write f32 Of[m*1024+n] + bias b0
template <int MODE>
__global__ __launch_bounds__(256, 2) void gemm_bt(
    const bf16* __restrict__ A, const bf16* __restrict__ Bt,
    const float* __restrict__ b0, const float* __restrict__ b1,
    const float* __restrict__ b2, bf16* __restrict__ O0,
    bf16* __restrict__ O1, bf16* __restrict__ O2, float* __restrict__ Of) {
  constexpr int Kd = DDIM;
  __shared__ bf16x8 lA[128 * 8];
  __shared__ bf16x8 lB[128 * 8];
  const int tid = threadIdx.x;
  const int wave = tid >> 6, lane = tid & 63;
  const int l15 = lane & 15, l4 = lane >> 4;
  const int wm = wave >> 1, wn = wave & 1;
  const int m0 = blockIdx.x * 128, n0 = blockIdx.y * 128;
  const f32x4 z = {0.f, 0.f, 0.f, 0.f};
  f32x4 acc[4][4];
#pragma unroll
  for (int i = 0; i < 4; ++i)
#pragma unroll
    for (int j = 0; j < 4; ++j) acc[i][j] = z;

  for (int k0 = 0; k0 < Kd; k0 += 64) {
#pragma unroll
    for (int j = 0; j < 4; ++j) {
      const int slot = j * 256 + tid;
      const int r = slot >> 3, cs = slot & 7;
      const int c = cs ^ (r & 7);  // pre-swizzled global source, linear LDS dest
      gload_lds16(A + (size_t)(m0 + r) * Kd + k0 + c * 8,
                  &lA[j * 256 + wave * 64]);
      gload_lds16(Bt + (size_t)(n0 + r) * Kd + k0 + c * 8,
                  &lB[j * 256 + wave * 64]);
    }
    __syncthreads();
    bf16x8 af[2][4], bfr[2][4];
#pragma unroll
    for (int ks = 0; ks < 2; ++ks) {
#pragma unroll
      for (int i = 0; i < 4; ++i) {
        const int ra = wm * 64 + i * 16 + l15;
        af[ks][i] = lA[ra * 8 + ((ks * 4 + l4) ^ (ra & 7))];
        const int rb = wn * 64 + i * 16 + l15;
        bfr[ks][i] = lB[rb * 8 + ((ks * 4 + l4) ^ (rb & 7))];
      }
    }
#pragma unroll
    for (int ks = 0; ks < 2; ++ks)
#pragma unroll
      for (int i = 0; i < 4; ++i)
#pragma unroll
        for (int j = 0; j < 4; ++j)
          acc[i][j] = mfma16(af[ks][i], bfr[ks][j], acc[i][j]);
    __syncthreads();
  }

  // C row m = m0 + wm*64 + i*16 + l4*4 + r ; col n = n0 + wn*64 + j*16 + l15
#pragma unroll
  for (int i = 0; i < 4; ++i) {
    const int m = m0 + wm * 64 + i * 16 + l4 * 4;
#pragma unroll
    for (int j = 0; j < 4; ++j) {
      const int n = n0 + wn * 64 + j * 16 + l15;
      if (MODE == 1) {
        const float bb = b0[n];
#pragma unroll
        for (int r = 0; r < 4; ++r)
          Of[(size_t)(m + r) * DDIM + n] = acc[i][j][r] + bb;
      } else {
        const int sel = n >> 10, nn = n & 1023;
        const int h = nn >> 6, d = nn & 63;
        const float* bp = sel == 0 ? b0 : (sel == 1 ? b1 : b2);
        const float bb = bp[nn];
        const int b = m >> 11, s = m & 2047;
        if (sel == 2) {
          union {
            bf16 h4[4];
            s16x4 v;
          } u;
#pragma unroll
          for (int r = 0; r < 4; ++r)
            u.h4[r] = __float2bfloat16(acc[i][j][r] + bb);
          *reinterpret_cast<s16x4*>(
              &O2[((size_t)(b * HH + h) * HDIM + d) * SS + s]) = u.v;
        } else {
#pragma unroll
          for (int r = 0; r < 4; ++r) {
            const float val = acc[i][j][r] + bb;
            (sel ? O1 : O0)[((size_t)(b * HH + h) * SS + (s + r)) * HDIM + d] =
                __float2bfloat16(val);
          }
        }
      }
    }
  }
}

// ---------------- fused flash attention (GEMM-image LDS pipeline) ----------
// grid.x = B*H*32; block = 256 (4 waves), wave owns 16 q-rows; kv-step 64.
// T14 reg-staging: per step issue next tile's K/V/bias global loads into
// registers (8x16B/thread), compute current step from LDS ONLY (swizzled
// ds_reads + MFMA + in-reg softmax), then ds_write staged regs (write-side
// XOR swizzle) into the other buffer; one barrier per step.
__global__ __launch_bounds__(256, 2) void attn_k(
    const bf16* __restrict__ Qb, const bf16* __restrict__ Kb,
    const bf16* __restrict__ Vt, const float* __restrict__ bias,
    const unsigned long long* __restrict__ mbits, bf16* __restrict__ ctx) {
  __shared__ bf16x8 lK[2][512];      // 2 x 64 keys x 64 hd  (8KB each)
  __shared__ bf16x8 lV[2][512];      // 2 x 64 d x 64 keys   (8KB each)
  __shared__ f32x4 lB[2][1024];      // 2 x 64 q x 64 k f32  (16KB each)
  __shared__ unsigned int plP[4 * 512];  // per-wave P scratch (8KB)
  const int tid = threadIdx.x;
  const int wave = tid >> 6, lane = tid & 63;
  const int l15 = lane & 15, l4 = lane >> 4;
  const int bid = blockIdx.x;
  const int qblk = bid & 31, bh = bid >> 5;
  const int b = bh >> 4, h = bh & 15;
  const int q0b = qblk * 64;
  const int q0w = q0b + wave * 16;

  const bf16* Qp = Qb + ((size_t)bh * SS + q0w) * HDIM;
  const bf16* Kp = Kb + (size_t)bh * SS * HDIM;
  const bf16* Vp = Vt + (size_t)bh * HDIM * SS;
  const float* Bb = bias + (size_t)h * SS * SS + (size_t)q0b * SS;
  unsigned int* plw = plP + wave * 512;

  // staging geometry: K/V = 512 chunks of 16B (2/thread), bias = 1024 (4/thr)
  const int rk0 = tid >> 3, ck0 = tid & 7;
  const int rk1 = 32 + rk0, ck1 = ck0;
  const int dk0 = rk0 * 8 + (ck0 ^ (rk0 & 7));
  const int dk1 = rk1 * 8 + (ck1 ^ (rk1 & 7));
  int rbv[4], cbv[4], dbv[4];
#pragma unroll
  for (int i = 0; i < 4; ++i) {
    const int sb = i * 256 + tid;
    rbv[i] = sb >> 4;
    cbv[i] = sb & 15;
    dbv[i] = rbv[i] * 16 + (cbv[i] ^ (rbv[i] & 7));
  }
  // bias read row = this wave's q row (tile rows cover q0b..q0b+63)
  const int brow = wave * 16 + l15;

  // ---- prologue: stage tile 0 ----
  {
    bf16x8 k0 = *reinterpret_cast<const bf16x8*>(Kp + (size_t)rk0 * HDIM + ck0 * 8);
    bf16x8 k1 = *reinterpret_cast<const bf16x8*>(Kp + (size_t)rk1 * HDIM + ck1 * 8);
    bf16x8 v0 = *reinterpret_cast<const bf16x8*>(Vp + (size_t)rk0 * SS + ck0 * 8);
    bf16x8 v1 = *reinterpret_cast<const bf16x8*>(Vp + (size_t)rk1 * SS + ck1 * 8);
    f32x4 b0 = *reinterpret_cast<const f32x4*>(Bb + (size_t)rbv[0] * SS + cbv[0] * 4);
    f32x4 b1 = *reinterpret_cast<const f32x4*>(Bb + (size_t)rbv[1] * SS + cbv[1] * 4);
    f32x4 b2 = *reinterpret_cast<const f32x4*>(Bb + (size_t)rbv[2] * SS + cbv[2] * 4);
    f32x4 b3 = *reinterpret_cast<const f32x4*>(Bb + (size_t)rbv[3] * SS + cbv[3] * 4);
    lK[0][dk0] = k0;
    lK[0][dk1] = k1;
    lV[0][dk0] = v0;
    lV[0][dk1] = v1;
    lB[0][dbv[0]] = b0;
    lB[0][dbv[1]] = b1;
    lB[0][dbv[2]] = b2;
    lB[0][dbv[3]] = b3;
  }

  bf16x8 qf[2];
#pragma unroll
  for (int ks = 0; ks < 2; ++ks)
    qf[ks] = *reinterpret_cast<const bf16x8*>(Qp + (size_t)l15 * HDIM +
                                              ks * 32 + l4 * 8);
  const f32x4 z = {0.f, 0.f, 0.f, 0.f};
  f32x4 o[4];
#pragma unroll
  for (int dd = 0; dd < 4; ++dd) o[dd] = z;
  float mrow = -1e30f, lrow = 0.f;

  __syncthreads();  // tile 0 visible

  for (int t = 0; t < 32; ++t) {
    const int cur = t & 1;
    const int kbn = (t + 1) * 64;
    const bool pf = t < 31;

    // (a) issue next-tile global loads into registers
    bf16x8 ks0, ks1, vs0, vs1;
    f32x4 bs0, bs1, bs2, bs3;
    if (pf) {
      ks0 = *reinterpret_cast<const bf16x8*>(Kp + (size_t)(kbn + rk0) * HDIM + ck0 * 8);
      ks1 = *reinterpret_cast<const bf16x8*>(Kp + (size_t)(kbn + rk1) * HDIM + ck1 * 8);
      vs0 = *reinterpret_cast<const bf16x8*>(Vp + (size_t)rk0 * SS + kbn + ck0 * 8);
      vs1 = *reinterpret_cast<const bf16x8*>(Vp + (size_t)rk1 * SS + kbn + ck1 * 8);
      bs0 = *reinterpret_cast<const f32x4*>(Bb + (size_t)rbv[0] * SS + kbn + cbv[0] * 4);
      bs1 = *reinterpret_cast<const f32x4*>(Bb + (size_t)rbv[1] * SS + kbn + cbv[1] * 4);
      bs2 = *reinterpret_cast<const f32x4*>(Bb + (size_t)rbv[2] * SS + kbn + cbv[2] * 4);
      bs3 = *reinterpret_cast<const f32x4*>(Bb + (size_t)rbv[3] * SS + kbn + cbv[3] * 4);
    }

    // (b) compute on buf[cur] — LDS only
    // QK^T (swapped): sc[jj][r] = S[k = t*64 + jj*16 + l4*4 + r][q = l15]
    f32x4 sc[4];
#pragma unroll
    for (int jj = 0; jj < 4; ++jj) {
      const int R = jj * 16 + l15;
      bf16x8 kf0 = lK[cur][R * 8 + ((0 + l4) ^ (R & 7))];
      bf16x8 kf1 = lK[cur][R * 8 + ((4 + l4) ^ (R & 7))];
      f32x4 s = mfma16(kf0, qf[0], z);
      s = mfma16(kf1, qf[1], s);
      sc[jj] = s;
    }
    // bias (LDS, swizzled, row = wave*16+l15) + scalar bitmask + softmax
    const unsigned long long mb = mbits[(b << 5) + t];
    float v[4][4];
    float bm = -1e30f;
#pragma unroll
    for (int jj = 0; jj < 4; ++jj) {
      const int byte =
          brow * 256 + ((((jj * 4 + l4) ^ (l15 & 7))) * 16);
      const f32x4 b4 = *reinterpret_cast<const f32x4*>(
          reinterpret_cast<const char*>(&lB[cur][0]) + byte);
      const unsigned nib = (unsigned)(mb >> (jj * 16 + l4 * 4)) & 15u;
#pragma unroll
      for (int r = 0; r < 4; ++r) {
        const float a = ((nib >> r) & 1u) ? -1e30f : b4[r];
        v[jj][r] = fmaf(sc[jj][r], 0.125f, a);
        bm = fmaxf(bm, v[jj][r]);
      }
    }
    bm = fmaxf(bm, __shfl_xor(bm, 16));
    bm = fmaxf(bm, __shfl_xor(bm, 32));
    const float mn = fmaxf(mrow, bm);
    const float alpha = __expf(mrow - mn);
    mrow = mn;
    float ps = 0.f;
    float p[4][4];
#pragma unroll
    for (int jj = 0; jj < 4; ++jj)
#pragma unroll
      for (int r = 0; r < 4; ++r) {
        p[jj][r] = __expf(v[jj][r] - mn);
        ps += p[jj][r];
      }
    ps += __shfl_xor(ps, 16);
    ps += __shfl_xor(ps, 32);
    lrow = lrow * alpha + ps;
    // pack P to per-wave LDS (XOR-swizzled)
#pragma unroll
    for (int jj = 0; jj < 4; ++jj)
#pragma unroll
      for (int r0 = 0; r0 < 4; r0 += 2) {
        union {
          bf16 h2[2];
          unsigned int w;
        } u;
        u.h2[0] = __float2bfloat16(p[jj][r0]);
        u.h2[1] = __float2bfloat16(p[jj][r0 + 1]);
        const int byte =
            (l15 * 128 + jj * 32 + l4 * 8 + r0 * 2) ^ ((l15 & 7) << 4);
        plw[byte >> 2] = u.w;
      }
    asm volatile("s_waitcnt lgkmcnt(0)" ::: "memory");
    bf16x8 pfr[2];
#pragma unroll
    for (int ks = 0; ks < 2; ++ks) {
      const int byte = (l15 * 128 + ks * 64 + l4 * 16) ^ ((l15 & 7) << 4);
      pfr[ks] = *reinterpret_cast<const bf16x8*>(
          reinterpret_cast<const char*>(plw) + byte);
    }
    // PV: V-frags from LDS
    float ar[4];
#pragma unroll
    for (int r = 0; r < 4; ++r) ar[r] = __shfl(alpha, l4 * 4 + r);
#pragma unroll
    for (int dd = 0; dd < 4; ++dd) {
      const int D = dd * 16 + l15;
      bf16x8 vf0 = lV[cur][D * 8 + ((0 + l4) ^ (D & 7))];
      bf16x8 vf1 = lV[cur][D * 8 + ((4 + l4) ^ (D & 7))];
#pragma unroll
      for (int r = 0; r < 4; ++r) o[dd][r] *= ar[r];
      o[dd] = mfma16(pfr[0], vf0, o[dd]);
      o[dd] = mfma16(pfr[1], vf1, o[dd]);
    }

    // (c) write staged regs -> buf[cur^1]
    if (pf) {
      const int nxt = cur ^ 1;
      lK[nxt][dk0] = ks0;
      lK[nxt][dk1] = ks1;
      lV[nxt][dk0] = vs0;
      lV[nxt][dk1] = vs1;
      lB[nxt][dbv[0]] = bs0;
      lB[nxt][dbv[1]] = bs1;
      lB[nxt][dbv[2]] = bs2;
      lB[nxt][dbv[3]] = bs3;
    }
    __syncthreads();
  }

  const float rl = 1.0f / lrow;
  float rlr[4];
#pragma unroll
  for (int r = 0; r < 4; ++r) rlr[r] = __shfl(rl, l4 * 4 + r);
#pragma unroll
  for (int dd = 0; dd < 4; ++dd) {
#pragma unroll
    for (int r = 0; r < 4; ++r) {
      const float val = o[dd][r] * rlr[r];
      const int s = q0w + l4 * 4 + r;
      ctx[((size_t)b * SS + s) * DDIM + h * HDIM + dd * 16 + l15] =
          __float2bfloat16(val);
    }
  }
}

extern "C" void kernel_launch(void* const* d_in, const int* in_sizes, int n_in,
                              void* d_out, int out_size, void* d_ws,
                              size_t ws_size, hipStream_t stream) {
  const float* x = (const float*)d_in[0];
  const float* abias = (const float*)d_in[1];
  const int* kpm = (const int*)d_in[2];
  const float* Wq = (const float*)d_in[3];
  const float* bq = (const float*)d_in[4];
  const float* Wk = (const float*)d_in[5];
  const float* bk = (const float*)d_in[6];
  const float* Wv = (const float*)d_in[7];
  const float* bv = (const float*)d_in[8];
  const float* Wo = (const float*)d_in[9];
  const float* bo = (const float*)d_in[10];
  float* out = (float*)d_out;

  char* ws = (char*)d_ws;
  bf16* xb = (bf16*)ws;                        // (B,S,D) bf16      8 MB
  bf16* Wt = (bf16*)(ws + 8388608);            // 3072x1024 bf16    6 MB
  bf16* Wot = (bf16*)(ws + 14680064);          // 1024x1024 bf16    2 MB
  bf16* Qb = (bf16*)(ws + 16777216);           // (B,H,S,HD)        8 MB
  bf16* Kb = (bf16*)(ws + 25165824);           // (B,H,S,HD)        8 MB
  bf16* Vtb = (bf16*)(ws + 33554432);          // (B,H,HD,S)        8 MB
  bf16* ctx = (bf16*)(ws + 41943040);          // (B,S,D) bf16      8 MB
  unsigned long long* mbits =
      (unsigned long long*)(ws + 50331648);    // 2*32 u64

  dim3 t256(256);
  cvt_k<<<dim3(2048), t256, 0, stream>>>(x, xb);
  transpose_cvt_k<<<dim3(16, 16), t256, 0, stream>>>(Wq, Wt);
  transpose_cvt_k<<<dim3(16, 16), t256, 0, stream>>>(Wk, Wt + 1024 * 1024);
  transpose_cvt_k<<<dim3(16, 16), t256, 0, stream>>>(Wv, Wt + 2 * 1024 * 1024);
  transpose_cvt_k<<<dim3(16, 16), t256, 0, stream>>>(Wo, Wot);
  mask_pack_k<<<dim3(1), dim3(64), 0, stream>>>(kpm, mbits);

  gemm_bt<0><<<dim3(32, 24), t256, 0, stream>>>(xb, Wt, bq, bk, bv, Qb, Kb,
                                                Vtb, nullptr);
  attn_k<<<dim3(1024), t256, 0, stream>>>(Qb, Kb, Vtb, abias, mbits, ctx);
  gemm_bt<1><<<dim3(32, 8), t256, 0, stream>>>(ctx, Wot, bo, nullptr, nullptr,
                                               nullptr, nullptr, nullptr, out);
}